// Round 1
// baseline (860.375 us; speedup 1.0000x reference)
//
#include <hip/hip_runtime.h>

// WhiteSoftmax: B=8192, C=64, O=128, 256 states, 256 vals.
// One thread per (b,c) chain: pack 128 x-bytes into 32 VGPRs, walk the
// 128-step state machine (dependent gathers, L2/L3-resident add_table),
// then gather softmax_table[s, x_o] and store float4.

constexpr int O_DIM = 128;
constexpr int NCHAINS = 8192 * 64;   // 524288 chains
constexpr int BLOCK = 256;

__global__ void ws_kernel(const int* __restrict__ x,
                          const int* __restrict__ add_table,
                          const float* __restrict__ st,
                          float* __restrict__ out) {
    const int chain = blockIdx.x * BLOCK + threadIdx.x;

    // ---- load x for this chain, pack 4 byte-values per dword ----
    const int4* xv = reinterpret_cast<const int4*>(x + (size_t)chain * O_DIM);
    unsigned px[32];
#pragma unroll
    for (int k = 0; k < 32; ++k) {
        int4 v = xv[k];
        px[k] = (unsigned)v.x | ((unsigned)v.y << 8) |
                ((unsigned)v.z << 16) | ((unsigned)v.w << 24);
    }

    // ---- 128-step dependent state walk ----
    int s = 0;
#pragma unroll
    for (int j = 0; j < O_DIM; ++j) {
        unsigned xj = (px[j >> 2] >> ((j & 3) * 8)) & 0xffu;
        s = add_table[(unsigned)(j << 16) | ((unsigned)s << 8) | xj];
    }

    // ---- output gather: one softmax_table row, 128 byte-indexed lookups ----
    const float* row = st + ((unsigned)s << 8);
    float4* ov = reinterpret_cast<float4*>(out + (size_t)chain * O_DIM);
#pragma unroll
    for (int k = 0; k < 32; ++k) {
        unsigned p = px[k];
        float4 r;
        r.x = row[p & 0xffu];
        r.y = row[(p >> 8) & 0xffu];
        r.z = row[(p >> 16) & 0xffu];
        r.w = row[p >> 24];
        ov[k] = r;
    }
}

extern "C" void kernel_launch(void* const* d_in, const int* in_sizes, int n_in,
                              void* d_out, int out_size, void* d_ws, size_t ws_size,
                              hipStream_t stream) {
    const int* x         = (const int*)d_in[0];
    const int* add_table = (const int*)d_in[1];
    const float* st      = (const float*)d_in[2];
    float* out           = (float*)d_out;

    ws_kernel<<<NCHAINS / BLOCK, BLOCK, 0, stream>>>(x, add_table, st, out);
}

// Round 3
// 387.478 us; speedup vs baseline: 2.2204x; 2.2204x over previous
//
#include <hip/hip_runtime.h>

// WhiteSoftmax: B=8192, C=64, O=128, 256 states, 256 vals.
// Block = 256 threads = 256 chains. Fully-coalesced x load -> byte-pack ->
// swizzled LDS; per-thread register walk of the 128-step state machine;
// coalesced output phase re-reading x-bytes from LDS.

constexpr int O_DIM = 128;
constexpr int NCHAINS = 8192 * 64;   // 524288 chains
constexpr int BLOCK = 256;
constexpr int CPB = 256;             // chains per block

typedef int   vi4 __attribute__((ext_vector_type(4)));
typedef float vf4 __attribute__((ext_vector_type(4)));

__global__ __launch_bounds__(BLOCK)
void ws_kernel(const int* __restrict__ x,
               const int* __restrict__ add_table,
               const float* __restrict__ st,
               float* __restrict__ out) {
    __shared__ unsigned px_lds[CPB * 32];   // 32 KB: 256 chains x 32 byte-packed dwords
    __shared__ int s_lds[CPB];

    const int t = threadIdx.x;
    const size_t chain0 = (size_t)blockIdx.x * CPB;

    // ---- phase 1: coalesced x load, pack, swizzled LDS write ----
    const vi4* xv = reinterpret_cast<const vi4*>(x + chain0 * O_DIM);
#pragma unroll 4
    for (int k = 0; k < 32; ++k) {
        const int idx = k * BLOCK + t;            // int4 index in block tile
        vi4 v = __builtin_nontemporal_load(&xv[idx]);
        unsigned p = (unsigned)v.x | ((unsigned)v.y << 8) |
                     ((unsigned)v.z << 16) | ((unsigned)v.w << 24);
        const int chain = idx >> 5;               // 32 dwords per chain
        const int d     = idx & 31;
        px_lds[chain * 32 + (d ^ (chain & 31))] = p;
    }
    __syncthreads();

    // ---- phase 2: own chain LDS -> regs (conflict-free), walk 128 steps ----
    unsigned px[32];
#pragma unroll
    for (int k = 0; k < 32; ++k)
        px[k] = px_lds[t * 32 + (k ^ (t & 31))];

    int s = 0;
#pragma unroll
    for (int j = 0; j < O_DIM; ++j) {
        unsigned xj = (px[j >> 2] >> ((j & 3) * 8)) & 0xffu;
        s = add_table[((unsigned)j << 16) | ((unsigned)s << 8) | xj];
    }
    s_lds[t] = s;
    __syncthreads();

    // ---- phase 3: coalesced output gather+store ----
    vf4* ov = reinterpret_cast<vf4*>(out + chain0 * O_DIM);
#pragma unroll 4
    for (int k = 0; k < 32; ++k) {
        const int idx   = k * BLOCK + t;          // float4 index in block tile
        const int chain = idx >> 5;               // 32 float4 per chain
        const int q     = idx & 31;
        unsigned p = px_lds[chain * 32 + (q ^ (chain & 31))];
        const float* row = st + ((unsigned)s_lds[chain] << 8);
        vf4 r;
        r.x = row[p & 0xffu];
        r.y = row[(p >> 8) & 0xffu];
        r.z = row[(p >> 16) & 0xffu];
        r.w = row[p >> 24];
        __builtin_nontemporal_store(r, &ov[idx]);
    }
}

extern "C" void kernel_launch(void* const* d_in, const int* in_sizes, int n_in,
                              void* d_out, int out_size, void* d_ws, size_t ws_size,
                              hipStream_t stream) {
    const int* x         = (const int*)d_in[0];
    const int* add_table = (const int*)d_in[1];
    const float* st      = (const float*)d_in[2];
    float* out           = (float*)d_out;

    ws_kernel<<<NCHAINS / CPB, BLOCK, 0, stream>>>(x, add_table, st, out);
}

// Round 4
// 345.660 us; speedup vs baseline: 2.4891x; 1.1210x over previous
//
#include <hip/hip_runtime.h>

// WhiteSoftmax: B=8192, C=64, O=128, 256 states, 256 vals.
// K0: pack add_table int32 -> u8 (8 MB in d_ws) so each j-slice is 64 KB
//     (L2-friendly, 4x less fill traffic, better gather hit rate).
// K1: 128 threads = 128 chains per block (LDS 16.9 KB -> 9 blocks/CU, ~56% occ).
//     Coalesced x load -> byte-pack -> swizzled LDS; per-thread register walk
//     of the 128-step state machine; coalesced output gather+store.

constexpr int O_DIM = 128;
constexpr int NCHAINS = 8192 * 64;          // 524288 chains
constexpr int BLOCK = 128;
constexpr int CPB = 128;                    // chains per block
constexpr int TAB_ENTRIES = 128 * 256 * 256;  // 8388608

typedef int   vi4 __attribute__((ext_vector_type(4)));
typedef float vf4 __attribute__((ext_vector_type(4)));

__global__ __launch_bounds__(256)
void pack_kernel(const int* __restrict__ t32, unsigned char* __restrict__ t8) {
    const int i = (blockIdx.x * 256 + threadIdx.x) * 4;
    vi4 v = *reinterpret_cast<const vi4*>(t32 + i);
    unsigned b = ((unsigned)v.x & 0xffu) | (((unsigned)v.y & 0xffu) << 8) |
                 (((unsigned)v.z & 0xffu) << 16) | (((unsigned)v.w & 0xffu) << 24);
    *reinterpret_cast<unsigned*>(t8 + i) = b;
}

template <typename TAB>
__global__ __launch_bounds__(BLOCK)
void ws_kernel(const int* __restrict__ x,
               const TAB* __restrict__ add_table,
               const float* __restrict__ st,
               float* __restrict__ out) {
    __shared__ unsigned px_lds[CPB * 32];   // 16 KB: byte-packed x, swizzled
    __shared__ int s_lds[CPB];

    const int t = threadIdx.x;
    const size_t chain0 = (size_t)blockIdx.x * CPB;

    // ---- phase 1: coalesced x load, pack, swizzled LDS write ----
    const vi4* xv = reinterpret_cast<const vi4*>(x + chain0 * O_DIM);
#pragma unroll 4
    for (int k = 0; k < 32; ++k) {
        const int idx = k * BLOCK + t;            // int4 index in block tile
        vi4 v = __builtin_nontemporal_load(&xv[idx]);
        unsigned p = (unsigned)v.x | ((unsigned)v.y << 8) |
                     ((unsigned)v.z << 16) | ((unsigned)v.w << 24);
        const int chain = idx >> 5;               // 32 dwords per chain
        const int d     = idx & 31;
        px_lds[chain * 32 + (d ^ (chain & 31))] = p;
    }
    __syncthreads();

    // ---- phase 2: own chain LDS -> regs (conflict-free), walk 128 steps ----
    unsigned px[32];
#pragma unroll
    for (int k = 0; k < 32; ++k)
        px[k] = px_lds[t * 32 + (k ^ (t & 31))];

    int s = 0;
#pragma unroll
    for (int j = 0; j < O_DIM; ++j) {
        unsigned xj = (px[j >> 2] >> ((j & 3) * 8)) & 0xffu;
        s = (int)add_table[((unsigned)j << 16) | ((unsigned)s << 8) | xj];
    }
    s_lds[t] = s;
    __syncthreads();

    // ---- phase 3: coalesced output gather+store ----
    vf4* ov = reinterpret_cast<vf4*>(out + chain0 * O_DIM);
#pragma unroll 4
    for (int k = 0; k < 32; ++k) {
        const int idx   = k * BLOCK + t;          // float4 index in block tile
        const int chain = idx >> 5;               // 32 float4 per chain
        const int q     = idx & 31;
        unsigned p = px_lds[chain * 32 + (q ^ (chain & 31))];
        const float* row = st + ((unsigned)s_lds[chain] << 8);
        vf4 r;
        r.x = row[p & 0xffu];
        r.y = row[(p >> 8) & 0xffu];
        r.z = row[(p >> 16) & 0xffu];
        r.w = row[p >> 24];
        __builtin_nontemporal_store(r, &ov[idx]);
    }
}

extern "C" void kernel_launch(void* const* d_in, const int* in_sizes, int n_in,
                              void* d_out, int out_size, void* d_ws, size_t ws_size,
                              hipStream_t stream) {
    const int* x         = (const int*)d_in[0];
    const int* add_table = (const int*)d_in[1];
    const float* st      = (const float*)d_in[2];
    float* out           = (float*)d_out;

    if (ws_size >= (size_t)TAB_ENTRIES) {
        unsigned char* t8 = (unsigned char*)d_ws;
        pack_kernel<<<TAB_ENTRIES / 4 / 256, 256, 0, stream>>>(add_table, t8);
        ws_kernel<unsigned char><<<NCHAINS / CPB, BLOCK, 0, stream>>>(x, t8, st, out);
    } else {
        ws_kernel<int><<<NCHAINS / CPB, BLOCK, 0, stream>>>(x, add_table, st, out);
    }
}